// Round 1
// 228.384 us; speedup vs baseline: 1.0857x; 1.0857x over previous
//
#include <hip/hip_runtime.h>
#include <hip/hip_bf16.h>

// Problem constants (B=1, H=W=64, C=768, nh=12, hd=64)
#define S_TOK 4096
#define CDIM  768
#define N3C   2304
#define NH    12
#define HD    64

#define LOG2E 1.44269504f

typedef __attribute__((ext_vector_type(8))) short short8;
typedef __attribute__((ext_vector_type(4))) short short4v;
typedef __attribute__((ext_vector_type(4))) float float4v;
typedef __attribute__((ext_vector_type(4))) unsigned uint4v;

__device__ __forceinline__ float b2f(short s) {
    return __uint_as_float(((unsigned)(unsigned short)s) << 16);
}
__device__ __forceinline__ short f2b(float f) {   // round-to-nearest-even
    unsigned u = __float_as_uint(f);
    unsigned r = (u + 0x7FFFu + ((u >> 16) & 1u)) >> 16;
    return (short)r;
}

#if __has_builtin(__builtin_amdgcn_exp2f)
#define EXP2F __builtin_amdgcn_exp2f
#else
#define EXP2F exp2f
#endif

// pack trunc-bf16(a) into low short, trunc-bf16(b) into high short
__device__ __forceinline__ unsigned pack_trunc(float a, float b) {
    return __builtin_amdgcn_perm(__float_as_uint(b), __float_as_uint(a), 0x07060302u);
}

__device__ __forceinline__ short8 u4_to_s8(unsigned a, unsigned b, unsigned c, unsigned d) {
    union { uint4v u; short8 s; } t;
    t.u = (uint4v){a, b, c, d};
    return t.s;
}

// ---------------------------------------------------------------------------
// Elementwise fp32 -> bf16 cast (4 elems/thread)
// ---------------------------------------------------------------------------
__global__ __launch_bounds__(256) void cast_bf16_kernel(
    const float* __restrict__ in, short* __restrict__ out, int n4)
{
    int i = blockIdx.x * 256 + threadIdx.x;
    if (i >= n4) return;
    float4 v = ((const float4*)in)[i];
    short4v o4 = { f2b(v.x), f2b(v.y), f2b(v.z), f2b(v.w) };
    *(short4v*)&out[(size_t)i * 4] = o4;
}

// ---------------------------------------------------------------------------
// Transpose + cast: in fp32 [R][C] -> out bf16 [C][R]. 64x64 tiles, 256 thr.
// ---------------------------------------------------------------------------
__global__ __launch_bounds__(256) void transpose_cast_kernel(
    const float* __restrict__ in, short* __restrict__ out, int R, int C)
{
    __shared__ float t[64][65];
    const int tid = threadIdx.x;
    const int c0 = blockIdx.x * 64, r0 = blockIdx.y * 64;
    const int li = tid >> 6;      // 0..3
    const int lj = tid & 63;
#pragma unroll
    for (int p = 0; p < 16; ++p) {
        int i = p * 4 + li;
        t[i][lj] = in[(size_t)(r0 + i) * C + c0 + lj];
    }
    __syncthreads();
#pragma unroll
    for (int p = 0; p < 16; ++p) {
        int i = p * 4 + li;
        out[(size_t)(c0 + i) * R + r0 + lj] = f2b(t[lj][i]);
    }
}

// ---------------------------------------------------------------------------
// MFMA GEMM core: C[128x128] = A[128xK] @ Bt[128xK]^T
// ---------------------------------------------------------------------------
#define GEMM_CORE(A_, Bt_)                                                     \
    __shared__ __align__(16) short a_s[128][72];                               \
    __shared__ __align__(16) short b_s[128][72];                               \
    const int tid  = threadIdx.x;                                              \
    const int m0 = blockIdx.y * 128;                                           \
    const int n0 = blockIdx.x * 128;                                           \
    const int lane = tid & 63, w = tid >> 6;                                   \
    const int l15 = lane & 15, quad = lane >> 4;                               \
    const int wr = w >> 1, wc = w & 1;                                         \
    const int srow = tid >> 1;                                                 \
    const int scol = (tid & 1) * 32;                                           \
    float4v acc[4][4];                                                         \
    _Pragma("unroll")                                                          \
    for (int i = 0; i < 4; ++i)                                                \
        _Pragma("unroll")                                                      \
        for (int j = 0; j < 4; ++j) acc[i][j] = (float4v){0.f,0.f,0.f,0.f};    \
    for (int k0 = 0; k0 < 768; k0 += 64) {                                     \
        __syncthreads();                                                       \
        const short* ga = A_ + (size_t)(m0 + srow) * 768 + k0 + scol;          \
        const short* gb = Bt_ + (size_t)(n0 + srow) * 768 + k0 + scol;         \
        _Pragma("unroll")                                                      \
        for (int v = 0; v < 4; ++v) {                                          \
            *(uint4*)&a_s[srow][scol + v*8] = *(const uint4*)(ga + v*8);       \
            *(uint4*)&b_s[srow][scol + v*8] = *(const uint4*)(gb + v*8);       \
        }                                                                      \
        __syncthreads();                                                       \
        _Pragma("unroll")                                                      \
        for (int kk = 0; kk < 64; kk += 32) {                                  \
            short8 af[4], bfr[4];                                              \
            _Pragma("unroll")                                                  \
            for (int i = 0; i < 4; ++i)                                        \
                af[i] = *(const short8*)&a_s[wr*64 + i*16 + l15][kk + quad*8]; \
            _Pragma("unroll")                                                  \
            for (int j = 0; j < 4; ++j)                                        \
                bfr[j] = *(const short8*)&b_s[wc*64 + j*16 + l15][kk + quad*8];\
            _Pragma("unroll")                                                  \
            for (int i = 0; i < 4; ++i)                                        \
                _Pragma("unroll")                                              \
                for (int j = 0; j < 4; ++j)                                    \
                    acc[i][j] = __builtin_amdgcn_mfma_f32_16x16x32_bf16(       \
                        af[i], bfr[j], acc[i][j], 0, 0, 0);                    \
        }                                                                      \
    }

// QKV GEMM: writes Qb[head][s][d], Kb[head][s][d], Vt[head][d][s] (bf16)
__global__ __launch_bounds__(256) void gemm_qkv_mfma(
    const short* __restrict__ A, const short* __restrict__ Bt,
    const float* __restrict__ bias,
    short* __restrict__ Qb, short* __restrict__ Kb, short* __restrict__ Vt)
{
    GEMM_CORE(A, Bt)

    const int sec = n0 / CDIM;      // tile fully inside one of q/k/v
    float bj[4];
#pragma unroll
    for (int j = 0; j < 4; ++j) bj[j] = bias[n0 + wc*64 + j*16 + l15];

    if (sec < 2) {
        short* dst = (sec == 0) ? Qb : Kb;
#pragma unroll
        for (int i = 0; i < 4; ++i)
#pragma unroll
            for (int j = 0; j < 4; ++j) {
                const int nn = (n0 + wc*64 + j*16 + l15) % CDIM;
                const int head = nn >> 6, d = nn & 63;
#pragma unroll
                for (int r = 0; r < 4; ++r) {
                    const int s = m0 + wr*64 + i*16 + quad*4 + r;
                    dst[((size_t)head * S_TOK + s) * HD + d] = f2b(acc[i][j][r] + bj[j]);
                }
            }
    } else {
#pragma unroll
        for (int i = 0; i < 4; ++i)
#pragma unroll
            for (int j = 0; j < 4; ++j) {
                const int nn = (n0 + wc*64 + j*16 + l15) % CDIM;
                const int head = nn >> 6, d = nn & 63;
                const int sbase = m0 + wr*64 + i*16 + quad*4;
                short4v v4;
#pragma unroll
                for (int r = 0; r < 4; ++r) v4[r] = f2b(acc[i][j][r] + bj[j]);
                *(short4v*)&Vt[((size_t)head * HD + d) * S_TOK + sbase] = v4;
            }
    }
}

// Proj GEMM: out fp32 [4096][768] = A @ Bt^T + bias
__global__ __launch_bounds__(256) void gemm_proj_mfma(
    const short* __restrict__ A, const short* __restrict__ Bt,
    const float* __restrict__ bias, float* __restrict__ out)
{
    GEMM_CORE(A, Bt)

    float bj[4];
#pragma unroll
    for (int j = 0; j < 4; ++j) bj[j] = bias[n0 + wc*64 + j*16 + l15];

#pragma unroll
    for (int i = 0; i < 4; ++i)
#pragma unroll
        for (int j = 0; j < 4; ++j) {
            const int n = n0 + wc*64 + j*16 + l15;
#pragma unroll
            for (int r = 0; r < 4; ++r) {
                const int s = m0 + wr*64 + i*16 + quad*4 + r;
                out[(size_t)s * CDIM + n] = acc[i][j][r] + bj[j];
            }
        }
}

// ---------------------------------------------------------------------------
// Rel-pos tables via MFMA. One block per (y, head); 64 queries s0=y*64..+63.
// Outputs are PRE-SCALED by log2e (flash computes softmax in exp2 domain).
// ---------------------------------------------------------------------------
__global__ __launch_bounds__(256) void rel_mfma_kernel(
    const short* __restrict__ Qb, const float* __restrict__ rph,
    const float* __restrict__ rpw, short* __restrict__ Relh,
    short* __restrict__ Relw)
{
    __shared__ __align__(16) short q_s [64][72];
    __shared__ __align__(16) short rh_s[64][72];
    __shared__ __align__(16) short rw_s[128][72];

    const int tid  = threadIdx.x;
    const int y    = blockIdx.x;
    const int head = blockIdx.y;
    const int s0   = y * 64;
    const int w = tid >> 6, lane = tid & 63;
    const int l15 = lane & 15, quad = lane >> 4;
    const int srow = tid >> 2;            // 0..63
    const int scol = (tid & 3) << 4;      // 0,16,32,48

    // ---- stage Q (bf16 passthrough) ----
    {
        const uint4* g = (const uint4*)(Qb + ((size_t)head * S_TOK + s0 + srow) * HD + scol);
        *(uint4*)&q_s[srow][scol]     = g[0];
        *(uint4*)&q_s[srow][scol + 8] = g[1];
    }
    // ---- stage rph rows y..y+63 (fp32 -> bf16) ----
    {
        const float* g = rph + (size_t)(y + srow) * HD + scol;
        short tmp[16];
#pragma unroll
        for (int i = 0; i < 16; i += 4) {
            float4 v = *(const float4*)(g + i);
            tmp[i] = f2b(v.x); tmp[i+1] = f2b(v.y); tmp[i+2] = f2b(v.z); tmp[i+3] = f2b(v.w);
        }
        *(short8*)&rh_s[srow][scol]     = *(short8*)&tmp[0];
        *(short8*)&rh_s[srow][scol + 8] = *(short8*)&tmp[8];
    }
    // ---- stage rpw rows 0..127 (row 127 clamped; never consumed) ----
#pragma unroll
    for (int half = 0; half < 2; ++half) {
        const int row = srow + half * 64;
        const int rr  = row > 126 ? 126 : row;
        const float* g = rpw + (size_t)rr * HD + scol;
        short tmp[16];
#pragma unroll
        for (int i = 0; i < 16; i += 4) {
            float4 v = *(const float4*)(g + i);
            tmp[i] = f2b(v.x); tmp[i+1] = f2b(v.y); tmp[i+2] = f2b(v.z); tmp[i+3] = f2b(v.w);
        }
        *(short8*)&rw_s[row][scol]     = *(short8*)&tmp[0];
        *(short8*)&rw_s[row][scol + 8] = *(short8*)&tmp[8];
    }
    __syncthreads();

    const short8 qa0 = *(const short8*)&q_s[w * 16 + l15][quad * 8];
    const short8 qa1 = *(const short8*)&q_s[w * 16 + l15][32 + quad * 8];

    // ---- relh: RH col j = y+jj, ky = 63-jj ----
#pragma unroll
    for (int ct = 0; ct < 4; ++ct) {
        const int jj = ct * 16 + l15;
        short8 b0 = *(const short8*)&rh_s[jj][quad * 8];
        short8 b1 = *(const short8*)&rh_s[jj][32 + quad * 8];
        float4v z = (float4v){0.f, 0.f, 0.f, 0.f};
        z = __builtin_amdgcn_mfma_f32_16x16x32_bf16(qa0, b0, z, 0, 0, 0);
        z = __builtin_amdgcn_mfma_f32_16x16x32_bf16(qa1, b1, z, 0, 0, 0);
        const int ky = 63 - jj;
#pragma unroll
        for (int r = 0; r < 4; ++r) {
            const int q = w * 16 + quad * 4 + r;
            Relh[((size_t)head * S_TOK + s0 + q) * HD + ky] = f2b(z[r] * LOG2E);
        }
    }

    // ---- relw: kx = q+63-j, keep 0<=kx<64 ----
#pragma unroll
    for (int ct = 0; ct < 8; ++ct) {
        const int j = ct * 16 + l15;
        short8 b0 = *(const short8*)&rw_s[j][quad * 8];
        short8 b1 = *(const short8*)&rw_s[j][32 + quad * 8];
        float4v z = (float4v){0.f, 0.f, 0.f, 0.f};
        z = __builtin_amdgcn_mfma_f32_16x16x32_bf16(qa0, b0, z, 0, 0, 0);
        z = __builtin_amdgcn_mfma_f32_16x16x32_bf16(qa1, b1, z, 0, 0, 0);
#pragma unroll
        for (int r = 0; r < 4; ++r) {
            const int q  = w * 16 + quad * 4 + r;
            const int kx = q + 63 - j;
            if (kx >= 0 && kx < 64)
                Relw[((size_t)head * S_TOK + s0 + q) * HD + kx] = f2b(z[r] * LOG2E);
        }
    }
}

// ---------------------------------------------------------------------------
// Flash attention v3: v2.5 minus the P LDS round-trip.
//   Key idea: stage K into LDS in BIT-PERMUTED row order so that S^T tile kt's
//   output rows land exactly on the keys this lane needs for the PV B-frags:
//     LDS row j holds key(j) = (j&3) + ((j>>2)&3)*8 + ((j>>4)&1)*4 + (j>>5)*32
//     => tile kt, lane (q,quad), reg r  <->  key  kbase(kt) + quad*8 + r,
//        kbase = {0,4,32,36}
//   Tiles 0,1 give keys quad*8+0..7 (pb0); tiles 2,3 give 32+quad*8+0..7 (pb1).
//   pb0/pb1 are assembled from the lane's own packed registers: no p_s, no
//   shuffles, no lgkmcnt-serialized LDS round trip. rel_w reads re-indexed to
//   the permuted keys; rel_h (chunk-uniform) and the ones-row denominator are
//   permutation-invariant.
// ---------------------------------------------------------------------------
__global__ __launch_bounds__(256, 3) void flash_kernel(
    const short* __restrict__ Qb, const short* __restrict__ Kb,
    const short* __restrict__ Vt, const short* __restrict__ Relh,
    const short* __restrict__ Relw, short* __restrict__ attn_b)
{
    __shared__ __align__(16) short k_s [2][64][72];   // [buf][perm key][d]
    __shared__ __align__(16) short vt_s[2][64][72];   // [buf][d][key]

    const int tid  = threadIdx.x;
    const int head = blockIdx.y;
    const int s0   = blockIdx.x * 64;
    const int w    = tid >> 6, lane = tid & 63;
    const int l15  = lane & 15, quad = lane >> 4;
    const int srow = tid >> 2, scol = (tid & 3) << 4;
    // K staging row permutation: key srow -> LDS row krow (j-bits from k-bits:
    // j0=k0 j1=k1 j2=k3 j3=k4 j4=k2 j5=k5)
    const int krow = (srow & 3) | (((srow >> 3) & 3) << 2)
                   | (((srow >> 2) & 1) << 4) | (srow & 32);

    const float C1 = 0.125f * LOG2E;
    const int q = w * 16 + l15;        // this lane's query index (fixed)

    // ---- Q B-frags (16 VGPRs, loaded once from global) ----
    short8 qb0, qb1;
    {
        const short* qrow = Qb + ((size_t)head * S_TOK + s0 + q) * HD;
        qb0 = *(const short8*)(qrow + quad * 8);
        qb1 = *(const short8*)(qrow + 32 + quad * 8);
    }

    // ---- relw -> 16 invariant VGPRs, permuted indexing:
    //      rw[kt][r] = Relw[q][ kbase(kt) + quad*8 + r ], kbase = {0,4,32,36}
    float rw[4][4];
    {
        const short* rwrow = Relw + ((size_t)head * S_TOK + s0 + q) * HD;
#pragma unroll
        for (int kt = 0; kt < 4; ++kt) {
            const int base = ((kt & 1) << 2) | ((kt >> 1) << 5);
            short4v v = *(const short4v*)(rwrow + base + quad * 8);
#pragma unroll
            for (int r = 0; r < 4; ++r) rw[kt][r] = b2f(v[r]);
        }
    }

    const short* rhrow = Relh + ((size_t)head * S_TOK + s0 + q) * HD;
    float rh_c = b2f(rhrow[0]);

    // ones A-frag for the denominator
    short8 aones;
#pragma unroll
    for (int j = 0; j < 8; ++j) aones[j] = (short)0x3F80;

    float4v od[4];                     // O^T tiles [dt]: col=q, row=d offset
#pragma unroll
    for (int dt = 0; dt < 4; ++dt) od[dt] = (float4v){0.f, 0.f, 0.f, 0.f};
    float4v dq = (float4v){0.f, 0.f, 0.f, 0.f};

    // ---- stage chunk 0 (K rows bit-permuted, V natural) ----
    const short* kbase = Kb + (size_t)head * S_TOK * HD + (size_t)srow * HD + scol;
    const short* vbase = Vt + ((size_t)head * HD + srow) * S_TOK + scol;
    {
        uint4 a = *(const uint4*)(kbase);
        uint4 b = *(const uint4*)(kbase + 8);
        uint4 c = *(const uint4*)(vbase);
        uint4 d = *(const uint4*)(vbase + 8);
        *(uint4*)&k_s[0][krow][scol]      = a;
        *(uint4*)&k_s[0][krow][scol + 8]  = b;
        *(uint4*)&vt_s[0][srow][scol]     = c;
        *(uint4*)&vt_s[0][srow][scol + 8] = d;
    }
    __syncthreads();

    for (int ic = 0; ic < 64; ++ic) {
        const int cur = ic & 1;

        // ---- issue next-chunk prefetch (lands during compute) ----
        uint4 pk0, pk1, pv0, pv1;
        short rhn;
        if (ic < 63) {
            const size_t ko = (size_t)(ic + 1) * 64 * HD;
            const int    vo = (ic + 1) * 64;
            pk0 = *(const uint4*)(kbase + ko);
            pk1 = *(const uint4*)(kbase + ko + 8);
            pv0 = *(const uint4*)(vbase + vo);
            pv1 = *(const uint4*)(vbase + vo + 8);
            rhn = rhrow[ic + 1];
        }

        // ---- S^T tiles 0,1 -> pb0 (keys quad*8+0..7, in-register) ----
        unsigned pk[8];
#pragma unroll
        for (int kt = 0; kt < 2; ++kt) {
            const short8 ka0 = *(const short8*)&k_s[cur][kt * 16 + l15][quad * 8];
            const short8 ka1 = *(const short8*)&k_s[cur][kt * 16 + l15][32 + quad * 8];
            float4v z = (float4v){0.f, 0.f, 0.f, 0.f};
            z = __builtin_amdgcn_mfma_f32_16x16x32_bf16(ka0, qb0, z, 0, 0, 0);
            z = __builtin_amdgcn_mfma_f32_16x16x32_bf16(ka1, qb1, z, 0, 0, 0);
            float p0 = EXP2F(C1 * z[0] + (rh_c + rw[kt][0]));
            float p1 = EXP2F(C1 * z[1] + (rh_c + rw[kt][1]));
            float p2 = EXP2F(C1 * z[2] + (rh_c + rw[kt][2]));
            float p3 = EXP2F(C1 * z[3] + (rh_c + rw[kt][3]));
            pk[kt * 2]     = pack_trunc(p0, p1);
            pk[kt * 2 + 1] = pack_trunc(p2, p3);
        }
        const short8 pb0 = u4_to_s8(pk[0], pk[1], pk[2], pk[3]);

        // ---- PV half 0 (keys 0..31) + denom; overlaps S^T tiles 2,3 ----
#pragma unroll
        for (int dt = 0; dt < 4; ++dt) {
            const short8 va0 = *(const short8*)&vt_s[cur][dt * 16 + l15][quad * 8];
            od[dt] = __builtin_amdgcn_mfma_f32_16x16x32_bf16(va0, pb0, od[dt], 0, 0, 0);
        }
        dq = __builtin_amdgcn_mfma_f32_16x16x32_bf16(aones, pb0, dq, 0, 0, 0);

        // ---- S^T tiles 2,3 -> pb1 (keys 32+quad*8+0..7) ----
#pragma unroll
        for (int kt = 2; kt < 4; ++kt) {
            const short8 ka0 = *(const short8*)&k_s[cur][kt * 16 + l15][quad * 8];
            const short8 ka1 = *(const short8*)&k_s[cur][kt * 16 + l15][32 + quad * 8];
            float4v z = (float4v){0.f, 0.f, 0.f, 0.f};
            z = __builtin_amdgcn_mfma_f32_16x16x32_bf16(ka0, qb0, z, 0, 0, 0);
            z = __builtin_amdgcn_mfma_f32_16x16x32_bf16(ka1, qb1, z, 0, 0, 0);
            float p0 = EXP2F(C1 * z[0] + (rh_c + rw[kt][0]));
            float p1 = EXP2F(C1 * z[1] + (rh_c + rw[kt][1]));
            float p2 = EXP2F(C1 * z[2] + (rh_c + rw[kt][2]));
            float p3 = EXP2F(C1 * z[3] + (rh_c + rw[kt][3]));
            pk[kt * 2]     = pack_trunc(p0, p1);
            pk[kt * 2 + 1] = pack_trunc(p2, p3);
        }
        const short8 pb1 = u4_to_s8(pk[4], pk[5], pk[6], pk[7]);

        // ---- PV half 1 (keys 32..63) + denom ----
#pragma unroll
        for (int dt = 0; dt < 4; ++dt) {
            const short8 va1 = *(const short8*)&vt_s[cur][dt * 16 + l15][32 + quad * 8];
            od[dt] = __builtin_amdgcn_mfma_f32_16x16x32_bf16(va1, pb1, od[dt], 0, 0, 0);
        }
        dq = __builtin_amdgcn_mfma_f32_16x16x32_bf16(aones, pb1, dq, 0, 0, 0);

        // ---- store prefetch to the other buffer; single barrier ----
        if (ic < 63) {
            *(uint4*)&k_s[cur ^ 1][krow][scol]      = pk0;
            *(uint4*)&k_s[cur ^ 1][krow][scol + 8]  = pk1;
            *(uint4*)&vt_s[cur ^ 1][srow][scol]     = pv0;
            *(uint4*)&vt_s[cur ^ 1][srow][scol + 8] = pv1;
            rh_c = b2f(rhn);
            __syncthreads();
        }
    }

    // ---- epilogue: denominator rows are equal -> inv per lane; b64 stores ----
    const float inv = 1.f / dq[0];
    short* outp = attn_b + (size_t)(s0 + q) * CDIM + head * HD;
#pragma unroll
    for (int dt = 0; dt < 4; ++dt) {
        short4v o4;
#pragma unroll
        for (int r = 0; r < 4; ++r) o4[r] = f2b(od[dt][r] * inv);
        *(short4v*)(outp + dt * 16 + quad * 4) = o4;
    }
}

// ---------------------------------------------------------------------------
extern "C" void kernel_launch(void* const* d_in, const int* in_sizes, int n_in,
                              void* d_out, int out_size, void* d_ws, size_t ws_size,
                              hipStream_t stream)
{
    const float* x    = (const float*)d_in[0];
    const float* qkvw = (const float*)d_in[1];
    const float* qkvb = (const float*)d_in[2];
    const float* rph  = (const float*)d_in[3];
    const float* rpw  = (const float*)d_in[4];
    const float* pw   = (const float*)d_in[5];
    const float* pb   = (const float*)d_in[6];
    float* out = (float*)d_out;

    // ws layout (shorts), total ~48.8 MB
    const size_t HSD = (size_t)NH * S_TOK * HD;   // 3,145,728
    short* xb     = (short*)d_ws;                 // 4096*768
    short* wt     = xb + (size_t)S_TOK * CDIM;    // 2304*768 (qkv_w^T)
    short* pwt    = wt + (size_t)N3C * CDIM;      // 768*768  (proj_w^T)
    short* Qb     = pwt + (size_t)CDIM * CDIM;
    short* Kb     = Qb + HSD;
    short* Vt     = Kb + HSD;
    short* Relh   = Vt + HSD;
    short* Relw   = Relh + HSD;
    short* attn_b = Relw + HSD;                   // 4096*768

    cast_bf16_kernel<<<S_TOK * CDIM / 4 / 256, 256, 0, stream>>>(x, xb, S_TOK * CDIM / 4);
    transpose_cast_kernel<<<dim3(N3C / 64, CDIM / 64), 256, 0, stream>>>(qkvw, wt, CDIM, N3C);
    transpose_cast_kernel<<<dim3(CDIM / 64, CDIM / 64), 256, 0, stream>>>(pw, pwt, CDIM, CDIM);

    gemm_qkv_mfma<<<dim3(N3C / 128, S_TOK / 128), 256, 0, stream>>>(
        xb, wt, qkvb, Qb, Kb, Vt);
    rel_mfma_kernel<<<dim3(64, NH), 256, 0, stream>>>(Qb, rph, rpw, Relh, Relw);
    flash_kernel<<<dim3(64, NH), 256, 0, stream>>>(Qb, Kb, Vt, Relh, Relw, attn_b);
    gemm_proj_mfma<<<dim3(CDIM / 128, S_TOK / 128), 256, 0, stream>>>(
        attn_b, pwt, pb, out);
}